// Round 2
// baseline (418.168 us; speedup 1.0000x reference)
//
#include <hip/hip_runtime.h>
#include <hip/hip_bf16.h>
#include <cstdint>

typedef _Float16 h8 __attribute__((ext_vector_type(8)));
typedef _Float16 h4 __attribute__((ext_vector_type(4)));
typedef float    f4 __attribute__((ext_vector_type(4)));

// Dims: B=16, Cin=256, Ch=128, Br=8, H=W=64, 4096 px/image, 65536 px total.
// ws layout (25 MB total — safe against small ws_size):
//   hr   @ 0          16,777,216 B  (f16 [65536 px][128 ch])
//   W1r  @ 16777216    4,718,592 B  (f16 [g][ci8][tap9][128c][32ch])
//   W2r  @ 21495808      524,288 B  (f16 [g][kc4][256co][32ch])
//   sel1 @ 22020096    2,097,152 B  (f32 [b][g][4096])
//   sel2 @ 24117248    2,097,152 B  (f32 [b][g][4096])

// ---------------- prep_w: fp32 -> f16 repack ----------------
__global__ __launch_bounds__(256) void prep_w_k(const float* __restrict__ W1,
        const float* __restrict__ W2, _Float16* __restrict__ W1r,
        _Float16* __restrict__ W2r) {
    int i = blockIdx.x * 256 + threadIdx.x;
    if (i < 2359296) {
        // W1 [g][c][ci][tap] -> W1r [g][ci>>5][tap][c][ci&31]
        int g = i / 294912;  int r  = i - g * 294912;
        int c = r / 2304;    int r2 = r - c * 2304;
        int ci = r2 / 9;     int tap = r2 - ci * 9;
        W1r[((((size_t)g * 8 + (ci >> 5)) * 9 + tap) * 128 + c) * 32 + (ci & 31)]
            = (_Float16)W1[i];
    } else {
        int i2 = i - 2359296;
        int g = i2 >> 15; int r = i2 & 32767; int co = r >> 7; int ch = r & 127;
        W2r[(((size_t)g * 4 + (ch >> 5)) * 256 + co) * 32 + (ch & 31)]
            = (_Float16)W2[i2];
    }
}

// ---------------- prep_x: sel1 softmax only ----------------
__global__ __launch_bounds__(256) void prep_x_k(const float* __restrict__ x,
        const float* __restrict__ Wc1, const float* __restrict__ bc1,
        float* __restrict__ sel1) {
    __shared__ float wc[2048];            // Wc1 [8][256]
    int t = threadIdx.x;
    for (int i = t; i < 2048; i += 256) wc[i] = Wc1[i];
    __syncthreads();
    int pix = blockIdx.x * 256 + t;       // b*4096 + p
    int b = pix >> 12, p = pix & 4095;
    const float* xp = x + (size_t)b * 1048576 + p;
    float lg[8] = {0.f,0.f,0.f,0.f,0.f,0.f,0.f,0.f};
    for (int c = 0; c < 256; ++c) {
        float v = fmaxf(xp[(size_t)c * 4096], 0.f);
        #pragma unroll
        for (int g = 0; g < 8; ++g) lg[g] += wc[g * 256 + c] * v;
    }
    float m = -1e30f;
    #pragma unroll
    for (int g = 0; g < 8; ++g) { lg[g] += bc1[g]; m = fmaxf(m, lg[g]); }
    float sum = 0.f;
    #pragma unroll
    for (int g = 0; g < 8; ++g) { lg[g] = __expf(lg[g] - m); sum += lg[g]; }
    float inv = 1.f / sum;
    #pragma unroll
    for (int g = 0; g < 8; ++g)
        sel1[(size_t)(b * 8 + g) * 4096 + p] = lg[g] * inv;
}

// ---------------- conv1: switched 3x3, implicit GEMM, 128ch x 128px tile ----
// Single-buffer LDS, 2-barrier protocol per stage (race-free by construction).
__global__ __launch_bounds__(256, 2) void conv1_k(const float* __restrict__ x,
        const _Float16* __restrict__ W1r, const float* __restrict__ sel1,
        const float* __restrict__ b1, _Float16* __restrict__ hr) {
    __shared__ _Float16 xs[4 * 64 * 40];     // 4 in-rows x 64 cols x 32ch (pad 40)
    __shared__ _Float16 wt[3 * 128 * 40];    // 3 taps x [128c][32ch pad 40]
    int t = threadIdx.x;
    int b = blockIdx.y, y0 = blockIdx.x * 2;
    int l = t & 63, w = t >> 6;
    int wm = w >> 1, wn = w & 1;
    int l15 = l & 15, kg = (l >> 4) * 8;
    const h8 HZ = {};
    const f4 FZ = {0.f, 0.f, 0.f, 0.f};
    f4 accf[4][4], acce[4][4];
    #pragma unroll
    for (int m = 0; m < 4; ++m)
        #pragma unroll
        for (int n = 0; n < 4; ++n) { accf[m][n] = FZ; acce[m][n] = FZ; }

    h8 wr[6];   // register prefetch of one 3-tap weight group (24,576 B / block)
    auto load_w = [&](int gg, int ky, int ci) {
        const _Float16* srcw = W1r + (size_t)((gg * 8 + ci) * 9 + ky * 3) * 4096;
        #pragma unroll
        for (int it = 0; it < 6; ++it)
            wr[it] = *(const h8*)(srcw + (size_t)(it * 256 + t) * 8);
    };
    auto write_w = [&]() {
        #pragma unroll
        for (int it = 0; it < 6; ++it) {
            int k = it * 256 + t;            // h8 index within 3-tap group
            int tap = k >> 9, j = k & 511;   // j: h8 within tap
            *(h8*)(wt + tap * 5120 + (j >> 2) * 40 + (j & 3) * 8) = wr[it];
        }
    };
    load_w(0, 0, 0);
    #pragma unroll 1
    for (int ci = 0; ci < 8; ++ci) {
        __syncthreads();      // all readers of xs (previous ci) done
        {   // stage relu(x) chunk: rows y0-1..y0+2, 64 cols, 32 ch (NCHW fp32 src)
            int r = t >> 6, col = t & 63;
            int yi = y0 - 1 + r;
            bool ok = (yi >= 0) && (yi < 64);
            const float* xp = x + ((size_t)(b * 256 + ci * 32)) * 4096 + yi * 64 + col;
            _Float16* dx = xs + (r * 64 + col) * 40;
            #pragma unroll
            for (int q = 0; q < 8; ++q) {
                h4 v = {};
                if (ok) {
                    #pragma unroll
                    for (int e = 0; e < 4; ++e)
                        v[e] = (_Float16)fmaxf(xp[(size_t)(q * 4 + e) * 4096], 0.f);
                }
                *(h4*)(dx + q * 4) = v;
            }
        }
        #pragma unroll 1
        for (int gg = 0; gg < 8; ++gg) {
            #pragma unroll 1
            for (int ky = 0; ky < 3; ++ky) {
                __syncthreads();   // readers of wt (previous group) done
                write_w();
                __syncthreads();   // wt visible (and xs on first group of ci)
                int nky = ky + 1, ngg = gg, nci = ci;
                if (nky == 3) { nky = 0; ++ngg; if (ngg == 8) { ngg = 0; ++nci; } }
                if (nci < 8) load_w(ngg, nky, nci);   // reg prefetch, hides latency
                #pragma unroll
                for (int kx = 0; kx < 3; ++kx) {
                    h8 af[4];
                    #pragma unroll
                    for (int m = 0; m < 4; ++m)
                        af[m] = *(const h8*)(wt + kx * 5120
                                             + (wm * 64 + m * 16 + l15) * 40 + kg);
                    #pragma unroll
                    for (int n = 0; n < 4; ++n) {
                        int p = wn * 64 + n * 16 + l15;
                        int ry = p >> 6, xc = p & 63;
                        int colx = xc + kx - 1;
                        h8 bf = HZ;
                        if (colx >= 0 && colx < 64)
                            bf = *(const h8*)(xs + ((ry + ky) * 64 + colx) * 40 + kg);
                        #pragma unroll
                        for (int m = 0; m < 4; ++m)
                            acce[m][n] = __builtin_amdgcn_mfma_f32_16x16x32_f16(
                                af[m], bf, acce[m][n], 0, 0, 0);
                    }
                }
            }
            // fold expert gg with per-pixel routing weight
            #pragma unroll
            for (int n = 0; n < 4; ++n) {
                int p = wn * 64 + n * 16 + l15;
                float s = sel1[(size_t)(b * 8 + gg) * 4096 + y0 * 64 + p];
                #pragma unroll
                for (int m = 0; m < 4; ++m) {
                    accf[m][n] += s * acce[m][n];
                    acce[m][n] = FZ;
                }
            }
        }
    }
    // epilogue: + b1, relu, f16, NHWC hr
    #pragma unroll
    for (int m = 0; m < 4; ++m) {
        int c0 = wm * 64 + m * 16 + (l >> 4) * 4;
        f4 bb = *(const f4*)(b1 + c0);
        #pragma unroll
        for (int n = 0; n < 4; ++n) {
            int p = wn * 64 + n * 16 + l15;
            size_t o = ((size_t)(b * 4096 + y0 * 64 + p)) * 128 + c0;
            h4 hv;
            #pragma unroll
            for (int r = 0; r < 4; ++r)
                hv[r] = (_Float16)fmaxf(accf[m][n][r] + bb[r], 0.f);
            *(h4*)(hr + o) = hv;
        }
    }
}

// ---------------- sel2: coupler-2 softmax from h ----------------
__global__ __launch_bounds__(256) void sel2_k(const _Float16* __restrict__ hr,
        const float* __restrict__ Wc2, const float* __restrict__ bc2,
        float* __restrict__ sel2) {
    __shared__ float wc[1024];   // Wc2 [8][128]
    int t = threadIdx.x;
    for (int i = t; i < 1024; i += 256) wc[i] = Wc2[i];
    __syncthreads();
    int pix = blockIdx.x * 256 + t;
    const h8* hp = (const h8*)(hr + (size_t)pix * 128);
    float lg[8] = {0.f,0.f,0.f,0.f,0.f,0.f,0.f,0.f};
    for (int j = 0; j < 16; ++j) {
        h8 v = hp[j];
        #pragma unroll
        for (int e = 0; e < 8; ++e) {
            float f = (float)v[e];
            int c = j * 8 + e;
            #pragma unroll
            for (int g = 0; g < 8; ++g) lg[g] += wc[g * 128 + c] * f;
        }
    }
    float m = -1e30f;
    #pragma unroll
    for (int g = 0; g < 8; ++g) { lg[g] += bc2[g]; m = fmaxf(m, lg[g]); }
    float sum = 0.f;
    #pragma unroll
    for (int g = 0; g < 8; ++g) { lg[g] = __expf(lg[g] - m); sum += lg[g]; }
    float inv = 1.f / sum;
    int b = pix >> 12, p = pix & 4095;
    #pragma unroll
    for (int g = 0; g < 8; ++g)
        sel2[(size_t)(b * 8 + g) * 4096 + p] = lg[g] * inv;
}

// ---------------- conv2: switched 1x1 + bias + residual, 256co x 64px tile ----
__global__ __launch_bounds__(256, 2) void conv2_k(const _Float16* __restrict__ hr,
        const _Float16* __restrict__ W2r, const float* __restrict__ sel2,
        const float* __restrict__ b2, const float* __restrict__ x,
        float* __restrict__ out) {
    __shared__ _Float16 hs[64 * 136];        // [64 px][128 ch pad 136]
    __shared__ _Float16 wt[256 * 40];        // [256 co][32 ch pad 40] single buf
    int t = threadIdx.x;
    int bid = blockIdx.x;
    int b = bid >> 6, p0 = (bid & 63) * 64;
    int l = t & 63, w = t >> 6;
    int wm = w >> 1, wn = w & 1;
    int l15 = l & 15, kg = (l >> 4) * 8;
    const f4 FZ = {0.f, 0.f, 0.f, 0.f};
    f4 acce[8][2], accf[8][2];
    #pragma unroll
    for (int m = 0; m < 8; ++m)
        #pragma unroll
        for (int n = 0; n < 2; ++n) { acce[m][n] = FZ; accf[m][n] = FZ; }
    {   // stage h tile (published by the first two barriers of the T loop)
        int px = t >> 2, qq = t & 3;
        const _Float16* src = hr + (size_t)(b * 4096 + p0 + px) * 128 + qq * 32;
        _Float16* dh = hs + px * 136 + qq * 32;
        #pragma unroll
        for (int u = 0; u < 4; ++u)
            *(h8*)(dh + u * 8) = *(const h8*)(src + u * 8);
    }
    h8 wr[4];
    auto load_w = [&](int T) {
        const _Float16* srcw = W2r + (size_t)T * 8192;
        #pragma unroll
        for (int it = 0; it < 4; ++it)
            wr[it] = *(const h8*)(srcw + (size_t)(it * 256 + t) * 8);
    };
    auto write_w = [&]() {
        #pragma unroll
        for (int it = 0; it < 4; ++it) {
            int cc = it * 256 + t;
            int c = cc >> 2, q = cc & 3;
            *(h8*)(wt + c * 40 + q * 8) = wr[it];
        }
    };
    load_w(0);
    #pragma unroll 1
    for (int T = 0; T < 32; ++T) {          // T = g*4 + kchunk
        __syncthreads();   // readers of wt (previous T) done
        write_w();
        __syncthreads();   // wt visible (and hs at T=0)
        if (T < 31) load_w(T + 1);
        int kc = (T & 3) * 32;
        h8 bf[2];
        #pragma unroll
        for (int n = 0; n < 2; ++n) {
            int px = wn * 32 + n * 16 + l15;
            bf[n] = *(const h8*)(hs + px * 136 + kc + kg);
        }
        #pragma unroll
        for (int m = 0; m < 8; ++m) {
            h8 af = *(const h8*)(wt + (wm * 128 + m * 16 + l15) * 40 + kg);
            #pragma unroll
            for (int n = 0; n < 2; ++n)
                acce[m][n] = __builtin_amdgcn_mfma_f32_16x16x32_f16(
                    af, bf[n], acce[m][n], 0, 0, 0);
        }
        if ((T & 3) == 3) {
            int g = T >> 2;
            #pragma unroll
            for (int n = 0; n < 2; ++n) {
                float s = sel2[(size_t)(b * 8 + g) * 4096 + p0 + wn * 32 + n * 16 + l15];
                #pragma unroll
                for (int m = 0; m < 8; ++m) { accf[m][n] += s * acce[m][n]; acce[m][n] = FZ; }
            }
        }
    }
    // epilogue: + b2 + residual x, fp32 NCHW out
    #pragma unroll
    for (int m = 0; m < 8; ++m) {
        int c0 = wm * 128 + m * 16 + (l >> 4) * 4;
        f4 bb = *(const f4*)(b2 + c0);
        #pragma unroll
        for (int n = 0; n < 2; ++n) {
            int px = wn * 32 + n * 16 + l15;
            size_t o = (size_t)(b * 256 + c0) * 4096 + p0 + px;
            #pragma unroll
            for (int r = 0; r < 4; ++r)
                out[o + (size_t)r * 4096] = accf[m][n][r] + bb[r] + x[o + (size_t)r * 4096];
        }
    }
}

extern "C" void kernel_launch(void* const* d_in, const int* in_sizes, int n_in,
                              void* d_out, int out_size, void* d_ws, size_t ws_size,
                              hipStream_t stream) {
    const float* x   = (const float*)d_in[0];
    const float* W1  = (const float*)d_in[1];
    const float* b1  = (const float*)d_in[2];
    const float* Wc1 = (const float*)d_in[3];
    const float* bc1 = (const float*)d_in[4];
    const float* W2  = (const float*)d_in[5];
    const float* b2  = (const float*)d_in[6];
    const float* Wc2 = (const float*)d_in[7];
    const float* bc2 = (const float*)d_in[8];
    float* out = (float*)d_out;
    char* ws = (char*)d_ws;
    _Float16* hr  = (_Float16*)(ws);                   // 16,777,216 B
    _Float16* W1r = (_Float16*)(ws + 16777216);        //  4,718,592 B
    _Float16* W2r = (_Float16*)(ws + 21495808);        //    524,288 B
    float* sel1   = (float*)(ws + 22020096);           //  2,097,152 B
    float* sel2   = (float*)(ws + 24117248);           //  2,097,152 B

    hipLaunchKernelGGL(prep_w_k, dim3(10240), dim3(256), 0, stream, W1, W2, W1r, W2r);
    hipLaunchKernelGGL(prep_x_k, dim3(256), dim3(256), 0, stream, x, Wc1, bc1, sel1);
    hipLaunchKernelGGL(conv1_k, dim3(32, 16), dim3(256), 0, stream, x, W1r, sel1, b1, hr);
    hipLaunchKernelGGL(sel2_k, dim3(256), dim3(256), 0, stream, hr, Wc2, bc2, sel2);
    hipLaunchKernelGGL(conv2_k, dim3(1024), dim3(256), 0, stream, hr, W2r, sel2, b2, x, out);
}